// Round 2
// baseline (819.620 us; speedup 1.0000x reference)
//
#include <hip/hip_runtime.h>

// ---------------------------------------------------------------------------
// FeatureAugmentationNetwork2: out = 0.5*F + 0.5*softmax((F Wq^T)(M Wk^T)^T) M
// N = M = 8192, H = 512, all fp32 in/out. Strategy: fp16 MFMA for all three
// matmul stages, fp32 online softmax, 4-way key-split flash attention.
// ---------------------------------------------------------------------------

typedef _Float16 half8 __attribute__((ext_vector_type(8)));
typedef float floatx4 __attribute__((ext_vector_type(4)));

#define MFMA16(a, b, c) __builtin_amdgcn_mfma_f32_16x16x32_f16((a), (b), (c), 0, 0, 0)

static constexpr int H = 512;
static constexpr int NROWS = 8192;

// ---------------------------------------------------------------------------
// K0a: cast Wq, Wk (512x512 fp32) to fp16.  524288 threads.
// ---------------------------------------------------------------------------
__global__ void castw_kernel(const float* __restrict__ wq, const float* __restrict__ wk,
                             _Float16* __restrict__ wq16, _Float16* __restrict__ wk16) {
    int i = blockIdx.x * 256 + threadIdx.x;  // 0 .. 524287
    if (i < 262144) wq16[i] = (_Float16)wq[i];
    else            wk16[i - 262144] = (_Float16)wk[i - 262144];
}

// ---------------------------------------------------------------------------
// K0b: pack V (= memory_features) into MFMA B-fragment order, fp16.
// Element V[key][d] with key = kb*32 + g*8 + j, d = db*16 + c  goes to
// vp[kb*16384 + db*512 + (g*16+c)*8 + j].  B-frag load for (key-tile kb,
// d-tile db) is then lane-contiguous: lane L reads 8 halves at L*8.
// ---------------------------------------------------------------------------
__global__ void packv_kernel(const float* __restrict__ mem, half8* __restrict__ vp) {
    int cid = blockIdx.x * 256 + threadIdx.x;  // 0 .. 524287 (chunks of 8 elems)
    int kb  = cid >> 11;
    int rem = cid & 2047;
    int db  = rem >> 6;
    int gc  = rem & 63;         // g*16 + c
    int g   = gc >> 4, c = gc & 15;
    const float* src = mem + (size_t)(kb * 32 + g * 8) * H + db * 16 + c;
    half8 v;
#pragma unroll
    for (int j = 0; j < 8; ++j) v[j] = (_Float16)src[(size_t)j * H];
    vp[cid] = v;
}

// ---------------------------------------------------------------------------
// K1: projection GEMM  out[row][col] = fp16( sum_h X[row][h]*W16[col][h] + b[col] )
// X fp32 [8192,512] (converted inline), W16 fp16 [512,512] row-major.
// Block: 256 thr = 4 waves; tile 64 rows x 64 cols; wave = 16-row stripe.
// ---------------------------------------------------------------------------
__global__ __launch_bounds__(256, 4)
void proj_kernel(const float* __restrict__ X, const _Float16* __restrict__ W16,
                 const float* __restrict__ bias, _Float16* __restrict__ out) {
    const int lane = threadIdx.x & 63;
    const int wave = threadIdx.x >> 6;
    const int row0 = blockIdx.x * 64 + wave * 16;
    const int col0 = blockIdx.y * 64;
    const int lr = lane & 15, lq = lane >> 4;

    floatx4 acc[4];
#pragma unroll
    for (int nt = 0; nt < 4; ++nt) { acc[nt][0] = 0.f; acc[nt][1] = 0.f; acc[nt][2] = 0.f; acc[nt][3] = 0.f; }

    const float* arow = X + (size_t)(row0 + lr) * H + lq * 8;
    const half8* wbase = (const half8*)W16;  // 64 half8 per row

#pragma unroll
    for (int kk = 0; kk < 16; ++kk) {
        floatx4 a0 = *(const floatx4*)(arow + kk * 32);
        floatx4 a1 = *(const floatx4*)(arow + kk * 32 + 4);
        half8 af;
        af[0] = (_Float16)a0[0]; af[1] = (_Float16)a0[1];
        af[2] = (_Float16)a0[2]; af[3] = (_Float16)a0[3];
        af[4] = (_Float16)a1[0]; af[5] = (_Float16)a1[1];
        af[6] = (_Float16)a1[2]; af[7] = (_Float16)a1[3];
#pragma unroll
        for (int nt = 0; nt < 4; ++nt) {
            half8 bf = wbase[(size_t)(col0 + nt * 16 + lr) * 64 + kk * 4 + lq];
            acc[nt] = MFMA16(af, bf, acc[nt]);
        }
    }
#pragma unroll
    for (int nt = 0; nt < 4; ++nt) {
        int col = col0 + nt * 16 + lr;
        float b = bias[col];
#pragma unroll
        for (int r = 0; r < 4; ++r) {
            int row = row0 + lq * 4 + r;
            out[(size_t)row * H + col] = (_Float16)(acc[nt][r] + b);
        }
    }
}

// ---------------------------------------------------------------------------
// K2: flash attention, 4-way key split.
// blockIdx.x = rb*4 + slice; rb in [0,128) owns 64 q-rows, slice owns 2048 keys.
// 4 waves, wave = 16-row stripe, full D=512 per wave (O = 128 VGPRs).
// Writes unnormalized O (fp16) + per-row m,l for the merge kernel.
// ---------------------------------------------------------------------------
__global__ __launch_bounds__(256, 2)
void flash_kernel(const _Float16* __restrict__ q16, const _Float16* __restrict__ k16,
                  const half8* __restrict__ vp, _Float16* __restrict__ opart,
                  float* __restrict__ mpart, float* __restrict__ lpart) {
    __shared__ half8 vlds[2048];            // 32 KB: one packed V key-tile (32 keys x 512)
    __shared__ _Float16 plds[4][16 * 40];   // per-wave P tile, padded stride 40

    const int lane = threadIdx.x & 63;
    const int wave = threadIdx.x >> 6;
    const int rb = blockIdx.x >> 2;
    const int slice = blockIdx.x & 3;
    const int row0 = rb * 64 + wave * 16;
    const int lr = lane & 15, lq = lane >> 4;

    // Q stripe preload: lane holds q16[row0+lr][kk*32 + lq*8 .. +8] for kk=0..15
    const half8* qrow = (const half8*)(q16 + (size_t)(row0 + lr) * H);
    half8 qf[16];
#pragma unroll
    for (int kk = 0; kk < 16; ++kk) qf[kk] = qrow[kk * 4 + lq];

    floatx4 o[32];
#pragma unroll
    for (int f = 0; f < 32; ++f) { o[f][0] = 0.f; o[f][1] = 0.f; o[f][2] = 0.f; o[f][3] = 0.f; }
    float m[4], l[4];
#pragma unroll
    for (int r = 0; r < 4; ++r) { m[r] = -1e30f; l[r] = 0.f; }

    _Float16* pw = plds[wave];

    for (int kt = slice * 64; kt < slice * 64 + 64; ++kt) {
        __syncthreads();  // previous tile's PV reads done before restaging vlds
        const half8* vsrc = vp + (size_t)kt * 2048;
#pragma unroll
        for (int i = 0; i < 8; ++i) vlds[threadIdx.x + i * 256] = vsrc[threadIdx.x + i * 256];

        // ---- QK^T: S[16 rows x 32 keys] ----
        const half8* kb0 = (const half8*)(k16 + (size_t)(kt * 32 + lr) * H) + lq;
        floatx4 s0 = {0.f, 0.f, 0.f, 0.f};
        floatx4 s1 = {0.f, 0.f, 0.f, 0.f};
#pragma unroll
        for (int kk = 0; kk < 16; ++kk) {
            half8 b0 = kb0[kk * 4];          // keys kt*32 + 0..15
            half8 b1 = kb0[1024 + kk * 4];   // keys kt*32 + 16..31 (16 rows * 64 half8)
            s0 = MFMA16(qf[kk], b0, s0);
            s1 = MFMA16(qf[kk], b1, s1);
        }

        // ---- online softmax (rows r owned by 16-lane groups) ----
        float al[4];
        int changed = 0;
#pragma unroll
        for (int r = 0; r < 4; ++r) {
            float mx = fmaxf(s0[r], s1[r]);
            mx = fmaxf(mx, __shfl_xor(mx, 1));
            mx = fmaxf(mx, __shfl_xor(mx, 2));
            mx = fmaxf(mx, __shfl_xor(mx, 4));
            mx = fmaxf(mx, __shfl_xor(mx, 8));
            float mn = fmaxf(m[r], mx);
            al[r] = __expf(m[r] - mn);
            changed |= (mx > m[r]) ? 1 : 0;
            float p0 = __expf(s0[r] - mn);
            float p1 = __expf(s1[r] - mn);
            s0[r] = p0; s1[r] = p1;
            float rs = p0 + p1;
            rs += __shfl_xor(rs, 1);
            rs += __shfl_xor(rs, 2);
            rs += __shfl_xor(rs, 4);
            rs += __shfl_xor(rs, 8);
            l[r] = l[r] * al[r] + rs;
            m[r] = mn;
        }
        if (__any(changed)) {
#pragma unroll
            for (int f = 0; f < 32; ++f) {
#pragma unroll
                for (int r = 0; r < 4; ++r) o[f][r] *= al[r];
            }
        }

        // ---- P (fp16) to LDS in A-fragment-readable layout ----
#pragma unroll
        for (int r = 0; r < 4; ++r) {
            pw[(lq * 4 + r) * 40 + lr]      = (_Float16)s0[r];
            pw[(lq * 4 + r) * 40 + 16 + lr] = (_Float16)s1[r];
        }
        __asm__ volatile("" ::: "memory");  // forbid reordering the read below above the writes
        half8 pf = *(const half8*)(pw + lr * 40 + lq * 8);

        __syncthreads();  // vlds staging complete

        // ---- PV: O[16 x 512] += P[16 x 32] @ V[32 x 512] ----
#pragma unroll
        for (int f = 0; f < 32; ++f) {
            o[f] = MFMA16(pf, vlds[f * 64 + lane], o[f]);
        }
    }

    // ---- write slice partials ----
    _Float16* ob = opart + (size_t)slice * NROWS * H;
#pragma unroll
    for (int f = 0; f < 32; ++f) {
#pragma unroll
        for (int r = 0; r < 4; ++r) {
            ob[(size_t)(row0 + lq * 4 + r) * H + f * 16 + lr] = (_Float16)o[f][r];
        }
    }
    if (lr == 0) {
#pragma unroll
        for (int r = 0; r < 4; ++r) {
            mpart[slice * NROWS + row0 + lq * 4 + r] = m[r];
            lpart[slice * NROWS + row0 + lq * 4 + r] = l[r];
        }
    }
}

// ---------------------------------------------------------------------------
// K3: merge 4 slice partials + blend with features.
// ---------------------------------------------------------------------------
__global__ void merge_kernel(const _Float16* __restrict__ opart, const float* __restrict__ mpart,
                             const float* __restrict__ lpart, const float* __restrict__ F,
                             float* __restrict__ out) {
    int idx = blockIdx.x * 256 + threadIdx.x;  // 0 .. 4194303
    int row = idx >> 9;
    float m0 = mpart[row], m1 = mpart[NROWS + row], m2 = mpart[2 * NROWS + row], m3 = mpart[3 * NROWS + row];
    float ms = fmaxf(fmaxf(m0, m1), fmaxf(m2, m3));
    float w0 = __expf(m0 - ms), w1 = __expf(m1 - ms), w2 = __expf(m2 - ms), w3 = __expf(m3 - ms);
    float denom = w0 * lpart[row] + w1 * lpart[NROWS + row] + w2 * lpart[2 * NROWS + row] + w3 * lpart[3 * NROWS + row];
    size_t stride = (size_t)NROWS * H;
    float num = w0 * (float)opart[idx] + w1 * (float)opart[stride + idx] +
                w2 * (float)opart[2 * stride + idx] + w3 * (float)opart[3 * stride + idx];
    out[idx] = 0.5f * F[idx] + 0.5f * (num / denom);
}

// ---------------------------------------------------------------------------
// Workspace layout (58 MB):
//   [ 0M,  8M) q16   fp16 [8192][512]
//   [ 8M, 16M) k16   fp16 [8192][512]
//   [16M, 24M) vp    fp16 packed V
//   [24M, 56M) opart fp16 [4][8192][512]
//   [56M, +128K) mpart fp32 [4][8192];  [56M+256K, +128K) lpart
//   [57M, +512K) wq16; [57M+512K, +512K) wk16
// ---------------------------------------------------------------------------
extern "C" void kernel_launch(void* const* d_in, const int* in_sizes, int n_in,
                              void* d_out, int out_size, void* d_ws, size_t ws_size,
                              hipStream_t stream) {
    const float* F   = (const float*)d_in[0];
    const float* Mem = (const float*)d_in[1];
    const float* Wq  = (const float*)d_in[2];
    const float* bq  = (const float*)d_in[3];
    const float* Wk  = (const float*)d_in[4];
    const float* bk  = (const float*)d_in[5];
    float* out = (float*)d_out;

    char* ws = (char*)d_ws;
    _Float16* q16   = (_Float16*)(ws);
    _Float16* k16   = (_Float16*)(ws + (8ull << 20));
    half8*    vp    = (half8*)(ws + (16ull << 20));
    _Float16* opart = (_Float16*)(ws + (24ull << 20));
    float*    mpart = (float*)(ws + (56ull << 20));
    float*    lpart = (float*)(ws + (56ull << 20) + (256ull << 10));
    _Float16* wq16  = (_Float16*)(ws + (57ull << 20));
    _Float16* wk16  = (_Float16*)(ws + (57ull << 20) + (512ull << 10));

    castw_kernel<<<2048, 256, 0, stream>>>(Wq, Wk, wq16, wk16);
    packv_kernel<<<2048, 256, 0, stream>>>(Mem, vp);
    proj_kernel<<<dim3(128, 8), 256, 0, stream>>>(F, wq16, bq, q16);
    proj_kernel<<<dim3(128, 8), 256, 0, stream>>>(Mem, wk16, bk, k16);
    flash_kernel<<<512, 256, 0, stream>>>(q16, k16, vp, opart, mpart, lpart);
    merge_kernel<<<16384, 256, 0, stream>>>(opart, mpart, lpart, F, out);
}

// Round 3
// 775.838 us; speedup vs baseline: 1.0564x; 1.0564x over previous
//
#include <hip/hip_runtime.h>

// ---------------------------------------------------------------------------
// out = 0.5*F + 0.5*softmax((F Wq^T)(M Wk^T)^T) M ;  N=M=8192, H=512, fp32.
// fp16 MFMA everywhere, fp32 online softmax, 4-way key-split flash attention.
// R3: K pre-packed to B-frag order (coalesced), 64-key tiles, DMA V staging.
// ---------------------------------------------------------------------------

typedef _Float16 half8 __attribute__((ext_vector_type(8)));
typedef float floatx4 __attribute__((ext_vector_type(4)));

#define MFMA16(a, b, c) __builtin_amdgcn_mfma_f32_16x16x32_f16((a), (b), (c), 0, 0, 0)

static constexpr int H = 512;
static constexpr int NROWS = 8192;

__device__ __forceinline__ void dma16(half8* lds_dst, const half8* g_src) {
    __builtin_amdgcn_global_load_lds(
        (const __attribute__((address_space(1))) unsigned int*)g_src,
        (__attribute__((address_space(3))) unsigned int*)lds_dst,
        16, 0, 0);
}

// ---------------------------------------------------------------------------
// K0a: cast Wq, Wk (512x512 fp32) to fp16.
// ---------------------------------------------------------------------------
__global__ void castw_kernel(const float* __restrict__ wq, const float* __restrict__ wk,
                             _Float16* __restrict__ wq16, _Float16* __restrict__ wk16) {
    int i = blockIdx.x * 256 + threadIdx.x;
    if (i < 262144) wq16[i] = (_Float16)wq[i];
    else            wk16[i - 262144] = (_Float16)wk[i - 262144];
}

// ---------------------------------------------------------------------------
// K0b: pack V (= memory_features) into MFMA B-frag order, fp16.
// V[key=kb*32+g*8+j][d=db*16+c] -> vp8[kb*2048 + db*64 + g*16+c][j]
// ---------------------------------------------------------------------------
__global__ void packv_kernel(const float* __restrict__ mem, half8* __restrict__ vp) {
    int cid = blockIdx.x * 256 + threadIdx.x;
    int kb  = cid >> 11;
    int rem = cid & 2047;
    int db  = rem >> 6;
    int gc  = rem & 63;
    int g   = gc >> 4, c = gc & 15;
    const float* src = mem + (size_t)(kb * 32 + g * 8) * H + db * 16 + c;
    half8 v;
#pragma unroll
    for (int j = 0; j < 8; ++j) v[j] = (_Float16)src[(size_t)j * H];
    vp[cid] = v;
}

// ---------------------------------------------------------------------------
// K0c: pack K (fp16 proj output) into QK B-frag order.
// Frag (t=key16-tile, kk): lane gc=g*16+c holds K[t*16+c][kk*32+g*8 .. +8]
// kp8[t*1024 + kk*64 + gc] = k16_8[(t*16+c)*64 + kk*4 + g]
// ---------------------------------------------------------------------------
__global__ void packk_kernel(const half8* __restrict__ k16v, half8* __restrict__ kp) {
    int cid = blockIdx.x * 256 + threadIdx.x;   // 524288
    int t   = cid >> 10;
    int rem = cid & 1023;
    int kk  = rem >> 6;
    int gc  = rem & 63;
    int g   = gc >> 4, c = gc & 15;
    kp[cid] = k16v[(size_t)(t * 16 + c) * 64 + kk * 4 + g];
}

// ---------------------------------------------------------------------------
// K1: projection GEMM  out = fp16(X @ W16^T + b), X fp32 converted inline.
// ---------------------------------------------------------------------------
__global__ __launch_bounds__(256, 4)
void proj_kernel(const float* __restrict__ X, const _Float16* __restrict__ W16,
                 const float* __restrict__ bias, _Float16* __restrict__ out) {
    const int lane = threadIdx.x & 63;
    const int wave = threadIdx.x >> 6;
    const int row0 = blockIdx.x * 64 + wave * 16;
    const int col0 = blockIdx.y * 64;
    const int lr = lane & 15, lq = lane >> 4;

    floatx4 acc[4];
#pragma unroll
    for (int nt = 0; nt < 4; ++nt) { acc[nt][0] = 0.f; acc[nt][1] = 0.f; acc[nt][2] = 0.f; acc[nt][3] = 0.f; }

    const float* arow = X + (size_t)(row0 + lr) * H + lq * 8;
    const half8* wbase = (const half8*)W16;

#pragma unroll
    for (int kk = 0; kk < 16; ++kk) {
        floatx4 a0 = *(const floatx4*)(arow + kk * 32);
        floatx4 a1 = *(const floatx4*)(arow + kk * 32 + 4);
        half8 af;
        af[0] = (_Float16)a0[0]; af[1] = (_Float16)a0[1];
        af[2] = (_Float16)a0[2]; af[3] = (_Float16)a0[3];
        af[4] = (_Float16)a1[0]; af[5] = (_Float16)a1[1];
        af[6] = (_Float16)a1[2]; af[7] = (_Float16)a1[3];
#pragma unroll
        for (int nt = 0; nt < 4; ++nt) {
            half8 bf = wbase[(size_t)(col0 + nt * 16 + lr) * 64 + kk * 4 + lq];
            acc[nt] = MFMA16(af, bf, acc[nt]);
        }
    }
#pragma unroll
    for (int nt = 0; nt < 4; ++nt) {
        int col = col0 + nt * 16 + lr;
        float b = bias[col];
#pragma unroll
        for (int r = 0; r < 4; ++r) {
            int row = row0 + lq * 4 + r;
            out[(size_t)row * H + col] = (_Float16)(acc[nt][r] + b);
        }
    }
}

// ---------------------------------------------------------------------------
// K2: flash attention. blockIdx.x = rb*4+slice; rb owns 64 q-rows, slice owns
// 2048 keys as 32 tiles of 64 keys. 4 waves x 16-row stripes, D=512 per wave.
// K frags from global (packed kp, coalesced); V tile DMA-staged to LDS.
// ---------------------------------------------------------------------------
__global__ __launch_bounds__(256, 2)
void flash_kernel(const _Float16* __restrict__ q16, const half8* __restrict__ kp,
                  const half8* __restrict__ vp, _Float16* __restrict__ opart,
                  float* __restrict__ mpart, float* __restrict__ lpart) {
    __shared__ half8 vlds[4096];            // 64 KB: 64 keys x 512 d, packed
    __shared__ _Float16 plds[4][16 * 72];   // per-wave 16x64 P tile, stride 72

    const int lane = threadIdx.x & 63;
    const int wave = threadIdx.x >> 6;
    const int rb = blockIdx.x >> 2;
    const int slice = blockIdx.x & 3;
    const int row0 = rb * 64 + wave * 16;
    const int lr = lane & 15, lq = lane >> 4;

    // Q stripe: lane holds q16[row0+lr][kk*32 + lq*8 .. +8], kk=0..15
    const half8* qrow = (const half8*)(q16 + (size_t)(row0 + lr) * H);
    half8 qf[16];
#pragma unroll
    for (int kk = 0; kk < 16; ++kk) qf[kk] = qrow[kk * 4 + lq];

    floatx4 o[32];
#pragma unroll
    for (int f = 0; f < 32; ++f) { o[f][0] = 0.f; o[f][1] = 0.f; o[f][2] = 0.f; o[f][3] = 0.f; }
    float m[4], l[4];
#pragma unroll
    for (int r = 0; r < 4; ++r) { m[r] = -1e30f; l[r] = 0.f; }

    _Float16* pw = plds[wave];

    for (int kt = slice * 32; kt < slice * 32 + 32; ++kt) {
        __syncthreads();  // previous tile's PV reads done before restaging vlds

        // ---- stage V tile (64 keys x 512) via async DMA, 16B per issue ----
        const half8* vsrc = vp + (size_t)kt * 4096;
#pragma unroll
        for (int i = 0; i < 16; ++i)
            dma16(&vlds[threadIdx.x + i * 256], &vsrc[threadIdx.x + i * 256]);

        // ---- QK^T: S[16 rows x 64 keys], K frags coalesced from global ----
        const half8* kbase = kp + (size_t)kt * 4096;
        floatx4 s[4];
#pragma unroll
        for (int c = 0; c < 4; ++c) { s[c][0] = 0.f; s[c][1] = 0.f; s[c][2] = 0.f; s[c][3] = 0.f; }
#pragma unroll
        for (int kk = 0; kk < 16; ++kk) {
#pragma unroll
            for (int c = 0; c < 4; ++c) {
                half8 b = kbase[c * 1024 + kk * 64 + lane];
                s[c] = MFMA16(qf[kk], b, s[c]);
            }
        }

        // ---- online softmax over 64 keys ----
        float al[4];
        int changed = 0;
#pragma unroll
        for (int r = 0; r < 4; ++r) {
            float mx = fmaxf(fmaxf(s[0][r], s[1][r]), fmaxf(s[2][r], s[3][r]));
            mx = fmaxf(mx, __shfl_xor(mx, 1));
            mx = fmaxf(mx, __shfl_xor(mx, 2));
            mx = fmaxf(mx, __shfl_xor(mx, 4));
            mx = fmaxf(mx, __shfl_xor(mx, 8));
            float mn = fmaxf(m[r], mx);
            al[r] = __expf(m[r] - mn);
            changed |= (mx > m[r]) ? 1 : 0;
            float rs = 0.f;
#pragma unroll
            for (int c = 0; c < 4; ++c) {
                float p = __expf(s[c][r] - mn);
                s[c][r] = p;
                rs += p;
            }
            rs += __shfl_xor(rs, 1);
            rs += __shfl_xor(rs, 2);
            rs += __shfl_xor(rs, 4);
            rs += __shfl_xor(rs, 8);
            l[r] = l[r] * al[r] + rs;
            m[r] = mn;
        }
        if (__any(changed)) {
#pragma unroll
            for (int f = 0; f < 32; ++f) {
#pragma unroll
                for (int r = 0; r < 4; ++r) o[f][r] *= al[r];
            }
        }

        // ---- P (fp16) -> LDS, re-read as two A-frags (keys 0..31, 32..63) ----
#pragma unroll
        for (int r = 0; r < 4; ++r) {
#pragma unroll
            for (int c = 0; c < 4; ++c)
                pw[(lq * 4 + r) * 72 + c * 16 + lr] = (_Float16)s[c][r];
        }
        __asm__ volatile("" ::: "memory");
        half8 pf0 = *(const half8*)(pw + lr * 72 + lq * 8);
        half8 pf1 = *(const half8*)(pw + lr * 72 + 32 + lq * 8);

        __syncthreads();  // V DMA complete

        // ---- PV: O[16 x 512] += P[16 x 64] @ V[64 x 512] ----
#pragma unroll
        for (int f = 0; f < 32; ++f) {
            o[f] = MFMA16(pf0, vlds[f * 64 + lane], o[f]);
            o[f] = MFMA16(pf1, vlds[2048 + f * 64 + lane], o[f]);
        }
    }

    // ---- write slice partials ----
    _Float16* ob = opart + (size_t)slice * NROWS * H;
#pragma unroll
    for (int f = 0; f < 32; ++f) {
#pragma unroll
        for (int r = 0; r < 4; ++r) {
            ob[(size_t)(row0 + lq * 4 + r) * H + f * 16 + lr] = (_Float16)o[f][r];
        }
    }
    if (lr == 0) {
#pragma unroll
        for (int r = 0; r < 4; ++r) {
            mpart[slice * NROWS + row0 + lq * 4 + r] = m[r];
            lpart[slice * NROWS + row0 + lq * 4 + r] = l[r];
        }
    }
}

// ---------------------------------------------------------------------------
// K3: merge 4 slice partials + blend with features.
// ---------------------------------------------------------------------------
__global__ void merge_kernel(const _Float16* __restrict__ opart, const float* __restrict__ mpart,
                             const float* __restrict__ lpart, const float* __restrict__ F,
                             float* __restrict__ out) {
    int idx = blockIdx.x * 256 + threadIdx.x;
    int row = idx >> 9;
    float m0 = mpart[row], m1 = mpart[NROWS + row], m2 = mpart[2 * NROWS + row], m3 = mpart[3 * NROWS + row];
    float ms = fmaxf(fmaxf(m0, m1), fmaxf(m2, m3));
    float w0 = __expf(m0 - ms), w1 = __expf(m1 - ms), w2 = __expf(m2 - ms), w3 = __expf(m3 - ms);
    float denom = w0 * lpart[row] + w1 * lpart[NROWS + row] + w2 * lpart[2 * NROWS + row] + w3 * lpart[3 * NROWS + row];
    size_t stride = (size_t)NROWS * H;
    float num = w0 * (float)opart[idx] + w1 * (float)opart[stride + idx] +
                w2 * (float)opart[2 * stride + idx] + w3 * (float)opart[3 * stride + idx];
    out[idx] = 0.5f * F[idx] + 0.5f * (num / denom);
}

// ---------------------------------------------------------------------------
// Workspace (66.5 MB):
//   [ 0M,  8M) q16    [ 8M, 16M) k16    [16M, 24M) vp     [24M, 32M) kp
//   [32M, 64M) opart  [64M, +128K) mpart  [64M+128K, +128K) lpart
//   [65M, +512K) wq16  [65M+512K, +512K) wk16
// ---------------------------------------------------------------------------
extern "C" void kernel_launch(void* const* d_in, const int* in_sizes, int n_in,
                              void* d_out, int out_size, void* d_ws, size_t ws_size,
                              hipStream_t stream) {
    const float* F   = (const float*)d_in[0];
    const float* Mem = (const float*)d_in[1];
    const float* Wq  = (const float*)d_in[2];
    const float* bq  = (const float*)d_in[3];
    const float* Wk  = (const float*)d_in[4];
    const float* bk  = (const float*)d_in[5];
    float* out = (float*)d_out;

    char* ws = (char*)d_ws;
    _Float16* q16   = (_Float16*)(ws);
    _Float16* k16   = (_Float16*)(ws + (8ull << 20));
    half8*    vp    = (half8*)(ws + (16ull << 20));
    half8*    kp    = (half8*)(ws + (24ull << 20));
    _Float16* opart = (_Float16*)(ws + (32ull << 20));
    float*    mpart = (float*)(ws + (64ull << 20));
    float*    lpart = (float*)(ws + (64ull << 20) + (128ull << 10));
    _Float16* wq16  = (_Float16*)(ws + (65ull << 20));
    _Float16* wk16  = (_Float16*)(ws + (65ull << 20) + (512ull << 10));

    castw_kernel<<<2048, 256, 0, stream>>>(Wq, Wk, wq16, wk16);
    packv_kernel<<<2048, 256, 0, stream>>>(Mem, vp);
    proj_kernel<<<dim3(128, 8), 256, 0, stream>>>(F, wq16, bq, q16);
    proj_kernel<<<dim3(128, 8), 256, 0, stream>>>(Mem, wk16, bk, k16);
    packk_kernel<<<2048, 256, 0, stream>>>((const half8*)k16, kp);
    flash_kernel<<<512, 256, 0, stream>>>(q16, kp, vp, opart, mpart, lpart);
    merge_kernel<<<16384, 256, 0, stream>>>(opart, mpart, lpart, F, out);
}

// Round 4
// 439.888 us; speedup vs baseline: 1.8632x; 1.7637x over previous
//
#include <hip/hip_runtime.h>

// ---------------------------------------------------------------------------
// out = 0.5*F + 0.5*softmax((F Wq^T)(M Wk^T)^T) M ;  N=M=8192, H=512, fp32.
// R4: flash rebuilt — K via global_load_lds (inline pack), PV d-partitioned
// across waves, trigger-based softmax (no per-tile shuffles on common path).
// ---------------------------------------------------------------------------

typedef _Float16 half8 __attribute__((ext_vector_type(8)));
typedef float floatx4 __attribute__((ext_vector_type(4)));

#define MFMA16(a, b, c) __builtin_amdgcn_mfma_f32_16x16x32_f16((a), (b), (c), 0, 0, 0)

static constexpr int H = 512;
static constexpr int NROWS = 8192;

__device__ __forceinline__ void dma16(half8* lds_dst, const void* g_src) {
    __builtin_amdgcn_global_load_lds(
        (const __attribute__((address_space(1))) unsigned int*)g_src,
        (__attribute__((address_space(3))) unsigned int*)lds_dst,
        16, 0, 0);
}

// ---------------------------------------------------------------------------
// K0a: cast Wq, Wk (512x512 fp32) to fp16.
// ---------------------------------------------------------------------------
__global__ void castw_kernel(const float* __restrict__ wq, const float* __restrict__ wk,
                             _Float16* __restrict__ wq16, _Float16* __restrict__ wk16) {
    int i = blockIdx.x * 256 + threadIdx.x;
    if (i < 262144) wq16[i] = (_Float16)wq[i];
    else            wk16[i - 262144] = (_Float16)wk[i - 262144];
}

// ---------------------------------------------------------------------------
// K0b: pack V into MFMA B-frag order, fp16.
// V[key=kb*32+g*8+j][d=db*16+c] -> vp8[kb*2048 + db*64 + g*16+c][j]
// ---------------------------------------------------------------------------
__global__ void packv_kernel(const float* __restrict__ mem, half8* __restrict__ vp) {
    int cid = blockIdx.x * 256 + threadIdx.x;
    int kb  = cid >> 11;
    int rem = cid & 2047;
    int db  = rem >> 6;
    int gc  = rem & 63;
    int g   = gc >> 4, c = gc & 15;
    const float* src = mem + (size_t)(kb * 32 + g * 8) * H + db * 16 + c;
    half8 v;
#pragma unroll
    for (int j = 0; j < 8; ++j) v[j] = (_Float16)src[(size_t)j * H];
    vp[cid] = v;
}

// ---------------------------------------------------------------------------
// K1: projection GEMM  out = fp16(X @ W16^T + b).
// ---------------------------------------------------------------------------
__global__ __launch_bounds__(256, 4)
void proj_kernel(const float* __restrict__ X, const _Float16* __restrict__ W16,
                 const float* __restrict__ bias, _Float16* __restrict__ out) {
    const int lane = threadIdx.x & 63;
    const int wave = threadIdx.x >> 6;
    const int row0 = blockIdx.x * 64 + wave * 16;
    const int col0 = blockIdx.y * 64;
    const int lr = lane & 15, lq = lane >> 4;

    floatx4 acc[4];
#pragma unroll
    for (int nt = 0; nt < 4; ++nt) { acc[nt][0] = 0.f; acc[nt][1] = 0.f; acc[nt][2] = 0.f; acc[nt][3] = 0.f; }

    const float* arow = X + (size_t)(row0 + lr) * H + lq * 8;
    const half8* wbase = (const half8*)W16;

#pragma unroll
    for (int kk = 0; kk < 16; ++kk) {
        floatx4 a0 = *(const floatx4*)(arow + kk * 32);
        floatx4 a1 = *(const floatx4*)(arow + kk * 32 + 4);
        half8 af;
        af[0] = (_Float16)a0[0]; af[1] = (_Float16)a0[1];
        af[2] = (_Float16)a0[2]; af[3] = (_Float16)a0[3];
        af[4] = (_Float16)a1[0]; af[5] = (_Float16)a1[1];
        af[6] = (_Float16)a1[2]; af[7] = (_Float16)a1[3];
#pragma unroll
        for (int nt = 0; nt < 4; ++nt) {
            half8 bf = wbase[(size_t)(col0 + nt * 16 + lr) * 64 + kk * 4 + lq];
            acc[nt] = MFMA16(af, bf, acc[nt]);
        }
    }
#pragma unroll
    for (int nt = 0; nt < 4; ++nt) {
        int col = col0 + nt * 16 + lr;
        float b = bias[col];
#pragma unroll
        for (int r = 0; r < 4; ++r) {
            int row = row0 + lq * 4 + r;
            out[(size_t)row * H + col] = (_Float16)(acc[nt][r] + b);
        }
    }
}

// ---------------------------------------------------------------------------
// K2: flash attention. blockIdx.x = rbk*4+slice; 64 q-rows per block, slice
// owns 2048 keys as 64 tiles of 32. QK: wave = 16-row stripe (K tile from
// LDS). PV: wave = 128-wide d-slice (P exchanged through LDS). Softmax:
// running m updated only when tile max exceeds m+10 (keeps fp16 P in range);
// rescale factors broadcast via LDS on trigger.
// ---------------------------------------------------------------------------
__global__ __launch_bounds__(256, 2)
void flash_kernel(const _Float16* __restrict__ q16, const _Float16* __restrict__ k16,
                  const half8* __restrict__ vp, _Float16* __restrict__ opart,
                  float* __restrict__ mpart, float* __restrict__ lpart) {
    __shared__ half8 klds[2048];          // 32 KB: K tile, B-frag order
    __shared__ half8 vlds[2048];          // 32 KB: V tile, packed order
    __shared__ _Float16 plds[64 * 36];    // 64 rows x 32 keys, stride 36
    __shared__ float alds[64];            // per-row rescale factors
    __shared__ float llds[64];            // final per-row l
    __shared__ int flagld;

    const int tid = threadIdx.x;
    const int lane = tid & 63;
    const int wave = tid >> 6;
    const int rbk = blockIdx.x >> 2;
    const int slice = blockIdx.x & 3;
    const int row0 = rbk * 64;
    const int lr = lane & 15, lq = lane >> 4;

    // K-DMA source offsets: LDS dst d = tid+i*256 -> (c,kk,g,cc);
    // src = (c*16+cc)*512 + kk*32 + g*8 halves within the 32-key K tile.
    int koff[8];
#pragma unroll
    for (int i = 0; i < 8; ++i) {
        int d = tid + i * 256;
        int c = d >> 10, kk = (d >> 6) & 15, g = (d >> 4) & 3, cc = d & 15;
        koff[i] = c * 8192 + cc * 512 + kk * 32 + g * 8;
    }

    // Q stripe for QK: lane holds q16[row0+wave*16+lr][kk*32+lq*8 ..]
    const half8* qrow = (const half8*)(q16 + (size_t)(row0 + wave * 16 + lr) * H);
    half8 qf[16];
#pragma unroll
    for (int kk = 0; kk < 16; ++kk) qf[kk] = qrow[kk * 4 + lq];

    floatx4 o[4][8];
#pragma unroll
    for (int rb = 0; rb < 4; ++rb)
#pragma unroll
        for (int f = 0; f < 8; ++f) { o[rb][f][0] = 0.f; o[rb][f][1] = 0.f; o[rb][f][2] = 0.f; o[rb][f][3] = 0.f; }
    float m[4], l[4];
#pragma unroll
    for (int r = 0; r < 4; ++r) { m[r] = -1e30f; l[r] = 0.f; }

    for (int kt = slice * 64; kt < slice * 64 + 64; ++kt) {
        __syncthreads();                                   // B1: prev tile consumed
        if (tid == 0) flagld = 0;

        const _Float16* ksrc = k16 + (size_t)kt * 16384;
        const half8* vsrc = vp + (size_t)kt * 2048;
#pragma unroll
        for (int i = 0; i < 8; ++i) dma16(&klds[tid + i * 256], ksrc + koff[i]);
#pragma unroll
        for (int i = 0; i < 8; ++i) dma16(&vlds[tid + i * 256], &vsrc[tid + i * 256]);

        __syncthreads();                                   // B2: DMA drained (vmcnt0)

        // ---- QK^T: S[16 x 32] per wave, K frags from LDS ----
        floatx4 s0 = {0.f, 0.f, 0.f, 0.f}, s1 = {0.f, 0.f, 0.f, 0.f};
#pragma unroll
        for (int kk = 0; kk < 16; ++kk) {
            s0 = MFMA16(qf[kk], klds[kk * 64 + lane], s0);
            s1 = MFMA16(qf[kk], klds[1024 + kk * 64 + lane], s1);
        }

        // ---- trigger check (no shuffles on common path) ----
        float tm[4]; int trig = 0;
#pragma unroll
        for (int r = 0; r < 4; ++r) {
            tm[r] = fmaxf(s0[r], s1[r]);
            trig |= (tm[r] > m[r] + 10.f) ? 1 : 0;
        }
        if (__any(trig)) {
            float al[4];
#pragma unroll
            for (int r = 0; r < 4; ++r) {
                float mx = tm[r];
                mx = fmaxf(mx, __shfl_xor(mx, 1));
                mx = fmaxf(mx, __shfl_xor(mx, 2));
                mx = fmaxf(mx, __shfl_xor(mx, 4));
                mx = fmaxf(mx, __shfl_xor(mx, 8));
                float mn = (mx > m[r] + 10.f) ? mx : m[r];
                al[r] = __expf(m[r] - mn);
                m[r] = mn;
                l[r] *= al[r];
            }
            if (lr == 0) {
#pragma unroll
                for (int r = 0; r < 4; ++r) alds[wave * 16 + lq * 4 + r] = al[r];
            }
            if (lane == 0) flagld = 1;
        } else {
            if (lr == 0) {
#pragma unroll
                for (int r = 0; r < 4; ++r) alds[wave * 16 + lq * 4 + r] = 1.0f;
            }
        }

        // ---- exp, l accumulate (lane-local), P -> LDS ----
#pragma unroll
        for (int r = 0; r < 4; ++r) {
            float p0 = __expf(s0[r] - m[r]);
            float p1 = __expf(s1[r] - m[r]);
            l[r] += p0 + p1;
            plds[(wave * 16 + lq * 4 + r) * 36 + lr]      = (_Float16)p0;
            plds[(wave * 16 + lq * 4 + r) * 36 + 16 + lr] = (_Float16)p1;
        }

        __syncthreads();                                   // B3: P + alds ready

        if (flagld) {
#pragma unroll
            for (int rb = 0; rb < 4; ++rb)
#pragma unroll
                for (int rr = 0; rr < 4; ++rr) {
                    float a = alds[rb * 16 + lq * 4 + rr];
#pragma unroll
                    for (int f = 0; f < 8; ++f) o[rb][f][rr] *= a;
                }
        }

        // ---- PV: wave owns d-slice [wave*128, +128); O[64 x 128] ----
        half8 pf[4];
#pragma unroll
        for (int rb = 0; rb < 4; ++rb)
            pf[rb] = *(const half8*)&plds[(rb * 16 + lr) * 36 + lq * 8];
#pragma unroll
        for (int f = 0; f < 8; ++f) {
            half8 vf = vlds[(wave * 8 + f) * 64 + lane];
#pragma unroll
            for (int rb = 0; rb < 4; ++rb) o[rb][f] = MFMA16(pf[rb], vf, o[rb][f]);
        }
    }

    // ---- final l reduction over the 16 lr lanes ----
#pragma unroll
    for (int r = 0; r < 4; ++r) {
        float lv = l[r];
        lv += __shfl_xor(lv, 1); lv += __shfl_xor(lv, 2);
        lv += __shfl_xor(lv, 4); lv += __shfl_xor(lv, 8);
        l[r] = lv;
    }
    if (lr == 0) {
#pragma unroll
        for (int r = 0; r < 4; ++r) {
            int row = wave * 16 + lq * 4 + r;
            llds[row] = l[r];
            mpart[slice * NROWS + row0 + row] = m[r];
            lpart[slice * NROWS + row0 + row] = l[r];
        }
    }
    __syncthreads();

    // ---- normalized O store (fp16) ----
    _Float16* ob = opart + (size_t)slice * NROWS * H;
#pragma unroll
    for (int rb = 0; rb < 4; ++rb) {
#pragma unroll
        for (int rr = 0; rr < 4; ++rr) {
            float linv = 1.0f / llds[rb * 16 + lq * 4 + rr];
            size_t row = row0 + rb * 16 + lq * 4 + rr;
#pragma unroll
            for (int f = 0; f < 8; ++f)
                ob[row * H + wave * 128 + f * 16 + lr] = (_Float16)(o[rb][f][rr] * linv);
        }
    }
}

// ---------------------------------------------------------------------------
// K3: merge normalized slice partials, weight = e^{m_s - max} * l_s.
// ---------------------------------------------------------------------------
__global__ void merge_kernel(const _Float16* __restrict__ opart, const float* __restrict__ mpart,
                             const float* __restrict__ lpart, const float* __restrict__ F,
                             float* __restrict__ out) {
    int idx = blockIdx.x * 256 + threadIdx.x;
    int row = idx >> 9;
    float m0 = mpart[row], m1 = mpart[NROWS + row], m2 = mpart[2 * NROWS + row], m3 = mpart[3 * NROWS + row];
    float ms = fmaxf(fmaxf(m0, m1), fmaxf(m2, m3));
    float w0 = __expf(m0 - ms) * lpart[row];
    float w1 = __expf(m1 - ms) * lpart[NROWS + row];
    float w2 = __expf(m2 - ms) * lpart[2 * NROWS + row];
    float w3 = __expf(m3 - ms) * lpart[3 * NROWS + row];
    float denom = w0 + w1 + w2 + w3;
    size_t stride = (size_t)NROWS * H;
    float num = w0 * (float)opart[idx] + w1 * (float)opart[stride + idx] +
                w2 * (float)opart[2 * stride + idx] + w3 * (float)opart[3 * stride + idx];
    out[idx] = 0.5f * F[idx] + 0.5f * (num / denom);
}

// ---------------------------------------------------------------------------
// Workspace (~59 MB):
//   [ 0M,  8M) q16   [ 8M, 16M) k16   [16M, 24M) vp   [24M, 56M) opart fp16
//   [56M,+128K) mpart  [+128K,+128K) lpart  [57M,+1M) wq16/wk16
// ---------------------------------------------------------------------------
extern "C" void kernel_launch(void* const* d_in, const int* in_sizes, int n_in,
                              void* d_out, int out_size, void* d_ws, size_t ws_size,
                              hipStream_t stream) {
    const float* F   = (const float*)d_in[0];
    const float* Mem = (const float*)d_in[1];
    const float* Wq  = (const float*)d_in[2];
    const float* bq  = (const float*)d_in[3];
    const float* Wk  = (const float*)d_in[4];
    const float* bk  = (const float*)d_in[5];
    float* out = (float*)d_out;

    char* ws = (char*)d_ws;
    _Float16* q16   = (_Float16*)(ws);
    _Float16* k16   = (_Float16*)(ws + (8ull << 20));
    half8*    vp    = (half8*)(ws + (16ull << 20));
    _Float16* opart = (_Float16*)(ws + (24ull << 20));
    float*    mpart = (float*)(ws + (56ull << 20));
    float*    lpart = (float*)(ws + (56ull << 20) + (128ull << 10));
    _Float16* wq16  = (_Float16*)(ws + (57ull << 20));
    _Float16* wk16  = (_Float16*)(ws + (57ull << 20) + (512ull << 10));

    castw_kernel<<<2048, 256, 0, stream>>>(Wq, Wk, wq16, wk16);
    packv_kernel<<<2048, 256, 0, stream>>>(Mem, vp);
    proj_kernel<<<dim3(128, 8), 256, 0, stream>>>(F, wq16, bq, q16);
    proj_kernel<<<dim3(128, 8), 256, 0, stream>>>(Mem, wk16, bk, k16);
    flash_kernel<<<512, 256, 0, stream>>>(q16, k16, vp, opart, mpart, lpart);
    merge_kernel<<<16384, 256, 0, stream>>>(opart, mpart, lpart, F, out);
}